// Round 12
// baseline (1806.880 us; speedup 1.0000x reference)
//
#include <hip/hip_runtime.h>

// Furthest Point Sampling, B=8, C=3, N=65536, NUM_POINTS=1024.
//
// R21 = R13 (proven best: 1400us) with ONE change: each exchange slot is
// padded to its OWN 128B cache line (stride 16 u64), so the 16 publishers
// write 16 distinct L2 lines (1 writer/line) and each polling wave reads 16
// lines served by distinct L2 banks in parallel.
//
// Why (unified contention model from R10/R12/R14/R20): every transport
// regression raised the PER-LINE access rate -- R20 2x poll issue = +240us,
// R14 4x pollers = +1240us, R12 4 writers/line = +330us -- monotone and
// steep. All 16 slots on ONE 128B line means 16 CUs' stores and 16 waves'
// continuous polls serialize at the single L2 bank owning that line;
// queuing inflates store-visibility AND poll RTT. R13 minimized the RATE
// given one line; R21 changes the LAYOUT: per-line rate drops ~16x while
// participant counts stay at the frozen optimum (16 pub + 16 poll, serial
// poll loop byte-identical to R13).
//
// WRITE_SIZE evidence says HBM cost is per-store (4224KB = 32 stores x 128B
// per iter, already line-granular), so traffic counters should stay flat;
// only latency should move.
//
// kRgn=2 (fits proven ws: 8 batches x 2 regions x 272 u64 x 8B = 34.8KB;
// R10 proved >= 65KB usable). Liveness proof for mod-2 rotation: block X
// publishes it+2 into region (it&1) only after X.poll-exit(it+1), which
// requires EVERY block published it+1, which requires their wave0
// poll-exit(it) and waves1-3 mailbox(it) -- so no reader still polls a
// region when it is overwritten. Harness poisons ws 0xAA per launch (tag
// 0xAAAA never matches it < 1024) -> layout change safe, no memset.
//
// Kept from R13 (byte-identical logic): DPP reduces; barrier-free s_wkey
// handoff; serial line-A poll with IC line-B fallback from round 2;
// speculative candidate-coord gather under the slot reduce; self-tagged
// 3-word LDS mailbox; XCD-measured placement; init path proven to run.
//
// Key packing (idx < 65536): dist_bits(32) | (0xFFFF - idx)(16) | it(16).
// Max key = max dist, tie -> smaller index == jnp.argmax first-occurrence
// (dist >= 0 -> float bits monotone; same tag on all keys of an iteration).
// Distance math: __fmul_rn/__fadd_rn (no FMA contraction) to bit-match numpy.

namespace {

constexpr int kB = 8;
constexpr int kN = 65536;
constexpr int kNP = 1024;
constexpr int kPB = 16;                      // slices (blocks) per batch
constexpr int kThreads = 256;
constexpr int kPPT = kN / (kPB * kThreads);  // 16 points per thread
constexpr int kGrp = kPPT / 4;               // 4 float4 groups
constexpr int kWaves = kThreads / 64;        // 4
constexpr int kRgn = 2;                      // region rotation (mod-2 proof above)
constexpr int kSlotStride = 16;              // u64 per slot = 128B = 1 L2 line
constexpr int kRgnStride = kPB * kSlotStride + kPB;  // 272 u64: lineA slots + lineB
constexpr int kBlocks = 256;

// One DPP max-reduce step on a u64 key. Invalid-lane handling: old = own
// value, bound_ctrl=false -> lanes with no source keep their own key; if the
// toolchain maps bound_ctrl to "write 0", max(key,0) is also a no-op for
// unsigned keys. Correct without row/bank masks either way.
template <int CTRL>
__device__ __forceinline__ unsigned long long dpp_max_u64(unsigned long long k) {
  const int lo = (int)(unsigned)k;
  const int hi = (int)(unsigned)(k >> 32);
  const unsigned plo = (unsigned)__builtin_amdgcn_update_dpp(lo, lo, CTRL, 0xF, 0xF, false);
  const unsigned phi = (unsigned)__builtin_amdgcn_update_dpp(hi, hi, CTRL, 0xF, 0xF, false);
  const unsigned long long p = ((unsigned long long)phi << 32) | plo;
  return p > k ? p : k;
}

// sc0 load: bypass L1, served by this XCD's L2 (the intra-XCD coherence point).
__device__ __forceinline__ unsigned long long load_l2(const unsigned long long* p) {
  unsigned long long v;
  asm volatile("global_load_dwordx2 %0, %1, off sc0\n\ts_waitcnt vmcnt(0)"
               : "=v"(v)
               : "v"(p)
               : "memory");
  return v;
}

// sc0 store: write-through to this XCD's L2.
__device__ __forceinline__ void store_l2(unsigned long long* p, unsigned long long v) {
  asm volatile("global_store_dwordx2 %0, %1, off sc0" ::"v"(p), "v"(v) : "memory");
}

__global__ __launch_bounds__(kThreads) void fps_kernel(const float* __restrict__ pts,
                                                       float* __restrict__ out,
                                                       unsigned long long* __restrict__ slots,
                                                       unsigned* __restrict__ ctrl) {
  // ctrl: [0:8) per-XCD registration counters, [8] done count, [9] spare rank.
  const int tid = threadIdx.x;
  const int lane = tid & 63;
  const int wave = tid >> 6;

  __shared__ int s_batch, s_slice;
  __shared__ unsigned long long s_wkey[kWaves];  // tag = key low 16 bits (== it)
  __shared__ unsigned long long s_mail[2][3];    // parity x 3 self-tagged {tag32|val32}
  __shared__ int s_hist[kNP];

  if (tid == 0) {
    unsigned xcc;
    asm volatile("s_getreg_b32 %0, hwreg(HW_REG_XCC_ID)" : "=s"(xcc));
    const int home = (int)(xcc & 7u);
    int batch = -1, slice = -1;
    const int pos = (int)atomicAdd(&ctrl[home], 1u);
    if (pos < kPB) {
      batch = home;
      slice = pos;
    }
    __hip_atomic_fetch_add(&ctrl[8], 1u, __ATOMIC_RELEASE, __HIP_MEMORY_SCOPE_AGENT);
    if (batch < 0) {
      while (__hip_atomic_load(&ctrl[8], __ATOMIC_ACQUIRE, __HIP_MEMORY_SCOPE_AGENT) <
             (unsigned)kBlocks) {
        __builtin_amdgcn_s_sleep(8);
      }
      int need = (int)atomicAdd(&ctrl[9], 1u);
      for (int j = 0; j < kB; ++j) {
        int have = (int)__hip_atomic_load(&ctrl[j], __ATOMIC_RELAXED, __HIP_MEMORY_SCOPE_AGENT);
        have = have > kPB ? kPB : have;
        const int vac = kPB - have;
        if (need < vac) {
          batch = j;
          slice = have + need;
          break;
        }
        need -= vac;
      }
    }
    s_batch = batch;
    s_slice = slice;
    // poison: tag 0xFFFF never matches it < 1024
    s_wkey[0] = s_wkey[1] = s_wkey[2] = s_wkey[3] = 0xFFFFull;
    s_mail[0][0] = s_mail[0][1] = s_mail[0][2] = 0xFFFFFFFF00000000ull;
    s_mail[1][0] = s_mail[1][1] = s_mail[1][2] = 0xFFFFFFFF00000000ull;
  }
  __syncthreads();

  const int batch = s_batch;
  const int slice = s_slice;
  if (batch < 0) return;  // unneeded spare

  const float* __restrict__ xb = pts + (size_t)batch * 3 * kN;
  const float* __restrict__ yb = xb + kN;
  const float* __restrict__ zb = xb + 2 * kN;

  // Register-resident coords: block owns [slice*4096, slice*4096+4096).
  const int sbase = slice * (kThreads * kPPT);
  const int base0 = sbase + tid * 4;
  float px[kPPT], py[kPPT], pz[kPPT], dist[kPPT];
#pragma unroll
  for (int g = 0; g < kGrp; ++g) {
    const int base = base0 + g * (kThreads * 4);
    const float4 vx = *reinterpret_cast<const float4*>(xb + base);
    const float4 vy = *reinterpret_cast<const float4*>(yb + base);
    const float4 vz = *reinterpret_cast<const float4*>(zb + base);
    px[g * 4 + 0] = vx.x; px[g * 4 + 1] = vx.y; px[g * 4 + 2] = vx.z; px[g * 4 + 3] = vx.w;
    py[g * 4 + 0] = vy.x; py[g * 4 + 1] = vy.y; py[g * 4 + 2] = vy.z; py[g * 4 + 3] = vy.w;
    pz[g * 4 + 0] = vz.x; pz[g * 4 + 1] = vz.y; pz[g * 4 + 2] = vz.z; pz[g * 4 + 3] = vz.w;
  }
#pragma unroll
  for (int k = 0; k < kPPT; ++k) dist[k] = 1e10f;

  // Seed: index 0 (uniform broadcast load).
  float qx = xb[0], qy = yb[0], qz = zb[0];

  unsigned long long* const sb = slots + (size_t)batch * kRgn * kRgnStride;

  for (int it = 1; it < kNP; ++it) {
    // --- update dists + per-thread argmax (ascending index, strict '>') ---
    float bd = -1.0f;
    int bi = 0;
#pragma unroll
    for (int g = 0; g < kGrp; ++g) {
#pragma unroll
      for (int j = 0; j < 4; ++j) {
        const int k = g * 4 + j;
        const float dx = px[k] - qx;
        const float dy = py[k] - qy;
        const float dz = pz[k] - qz;
        const float ss =
            __fadd_rn(__fadd_rn(__fmul_rn(dx, dx), __fmul_rn(dy, dy)), __fmul_rn(dz, dz));
        const float nd = fminf(dist[k], ss);
        dist[k] = nd;
        if (nd > bd) {
          bd = nd;
          bi = base0 + g * (kThreads * 4) + j;
        }
      }
    }

    // key: dist(32) | (0xFFFF - idx)(16) | it(16)  -- tag self-validates.
    unsigned long long key = ((unsigned long long)__float_as_uint(bd) << 32) |
                             ((unsigned long long)(0xFFFFu - (unsigned)bi) << 16) |
                             (unsigned long long)(unsigned)it;

    // --- wave reduce at VALU speed: row_shr 1/2/4/8 + bcast15/31 -> lane 63 ---
    key = dpp_max_u64<0x111>(key);  // row_shr:1
    key = dpp_max_u64<0x112>(key);  // row_shr:2
    key = dpp_max_u64<0x114>(key);  // row_shr:4
    key = dpp_max_u64<0x118>(key);  // row_shr:8
    key = dpp_max_u64<0x142>(key);  // row_bcast:15
    key = dpp_max_u64<0x143>(key);  // row_bcast:31

    // --- barrier-free handoff: lane 63 ds_writes the wave key (self-tagged) ---
    if (lane == 63) {
      __hip_atomic_store(&s_wkey[wave], key, __ATOMIC_RELAXED, __HIP_MEMORY_SCOPE_WORKGROUP);
    }

    if (wave == 0) {
      // --- tag-poll the 4 wave keys (same-address broadcast, no conflicts) ---
      unsigned long long bk;
      for (;;) {
        bk = __hip_atomic_load(&s_wkey[lane & (kWaves - 1)], __ATOMIC_RELAXED,
                               __HIP_MEMORY_SCOPE_WORKGROUP);
        if (__all((unsigned)(bk & 0xFFFFull) == (unsigned)it)) break;
      }
      // --- block reduce over 4 wave keys: 2x quad_perm xor -> all lanes ---
      bk = dpp_max_u64<0xB1>(bk);  // quad_perm {1,0,3,2} = xor 1
      bk = dpp_max_u64<0x4E>(bk);  // quad_perm {2,3,0,1} = xor 2

      unsigned long long* const rgn = sb + (size_t)(it & (kRgn - 1)) * kRgnStride;
      if (lane == 0) {
        // primary: own 128B line in this XCD's L2 (1 writer per line)
        store_l2(rgn + slice * kSlotStride, bk);
        __hip_atomic_store(rgn + kPB * kSlotStride + slice, bk, __ATOMIC_RELAXED,
                           __HIP_MEMORY_SCOPE_AGENT);  // fallback: IC
      }

      // --- poll line A (16 distinct lines, parallel L2 banks) from round 0;
      //     merge IC line B from round 2 -- structure identical to R13 ---
      const unsigned long long* const pa = rgn + (lane & (kPB - 1)) * kSlotStride;
      const unsigned long long* const pb = rgn + kPB * kSlotStride + (lane & (kPB - 1));
      unsigned long long sv;
      int round = 0;
      for (;;) {
        unsigned long long a = load_l2(pa);
        bool ok = (unsigned)(a & 0xFFFFull) == (unsigned)it;
        if (round >= 2 && !ok) {
          const unsigned long long fb =
              __hip_atomic_load(pb, __ATOMIC_RELAXED, __HIP_MEMORY_SCOPE_AGENT);
          if ((unsigned)(fb & 0xFFFFull) == (unsigned)it) {
            a = fb;
            ok = true;
          }
        }
        if (__all(ok)) {
          sv = a;
          break;
        }
        ++round;
      }

      // --- speculative candidate-coord gather: issued before the VALU-only
      //     slot reduce; the loads complete underneath it ---
      const int cand = (int)(0xFFFFu - ((unsigned)(sv >> 16) & 0xFFFFu));
      const float gx = xb[cand];
      const float gy = yb[cand];
      const float gz = zb[cand];

      // --- 16-slot reduce: xor1, xor2, xor7, xor15 -> all lanes hold winner ---
      unsigned long long k2 = sv;
      k2 = dpp_max_u64<0xB1>(k2);   // quad_perm xor 1
      k2 = dpp_max_u64<0x4E>(k2);   // quad_perm xor 2
      k2 = dpp_max_u64<0x141>(k2);  // row_half_mirror = xor 7
      k2 = dpp_max_u64<0x140>(k2);  // row_mirror = xor 15

      // Winner coords: exactly the lanes whose slot held k2 match; pull their
      // speculative gather via readlane (src is wave-uniform).
      const unsigned long long m = __ballot(sv == k2);
      const int src = (int)__ffsll(m) - 1;
      qx = __int_as_float(__builtin_amdgcn_readlane(__float_as_int(gx), src));
      qy = __int_as_float(__builtin_amdgcn_readlane(__float_as_int(gy), src));
      qz = __int_as_float(__builtin_amdgcn_readlane(__float_as_int(gz), src));

      if (lane == 0) {
        const int p = it & 1;
        const unsigned long long t = (unsigned long long)(unsigned)it << 32;
        __hip_atomic_store(&s_mail[p][0], t | (unsigned)__float_as_uint(qx),
                           __ATOMIC_RELAXED, __HIP_MEMORY_SCOPE_WORKGROUP);
        __hip_atomic_store(&s_mail[p][1], t | (unsigned)__float_as_uint(qy),
                           __ATOMIC_RELAXED, __HIP_MEMORY_SCOPE_WORKGROUP);
        __hip_atomic_store(&s_mail[p][2], t | (unsigned)__float_as_uint(qz),
                           __ATOMIC_RELAXED, __HIP_MEMORY_SCOPE_WORKGROUP);
        s_hist[it] = (int)(0xFFFFu - ((unsigned)(k2 >> 16) & 0xFFFFu));
      }
    } else {
      // --- non-leader waves: probe 3 self-tagged words in one LDS round trip;
      //     exit with coords in hand (no dependent follow-up read) ---
      const int p = it & 1;
      unsigned long long w0, w1, w2;
      do {
        w0 = __hip_atomic_load(&s_mail[p][0], __ATOMIC_RELAXED, __HIP_MEMORY_SCOPE_WORKGROUP);
        w1 = __hip_atomic_load(&s_mail[p][1], __ATOMIC_RELAXED, __HIP_MEMORY_SCOPE_WORKGROUP);
        w2 = __hip_atomic_load(&s_mail[p][2], __ATOMIC_RELAXED, __HIP_MEMORY_SCOPE_WORKGROUP);
      } while (!((unsigned)(w0 >> 32) == (unsigned)it &&
                 (unsigned)(w1 >> 32) == (unsigned)it &&
                 (unsigned)(w2 >> 32) == (unsigned)it));
      qx = __int_as_float((int)(unsigned)w0);
      qy = __int_as_float((int)(unsigned)w1);
      qz = __int_as_float((int)(unsigned)w2);
    }
  }

  __syncthreads();  // make s_hist (written by wave 0) visible to all waves

  // --- gather: out[b][c][j] = points[b][c][idx_j]; slice-0 block per batch ---
  if (slice == 0) {
    float* __restrict__ ob = out + (size_t)batch * 3 * kNP;
    for (int j = tid; j < kNP; j += kThreads) {
      const int id = (j == 0) ? 0 : s_hist[j];
      ob[j] = xb[id];
      ob[kNP + j] = yb[id];
      ob[2 * kNP + j] = zb[id];
    }
  }
}

}  // namespace

extern "C" void kernel_launch(void* const* d_in, const int* in_sizes, int n_in,
                              void* d_out, int out_size, void* d_ws, size_t ws_size,
                              hipStream_t stream) {
  (void)in_sizes;
  (void)n_in;
  (void)out_size;
  (void)ws_size;
  const float* pts = (const float*)d_in[0];
  float* out = (float*)d_out;
  // ws: [0,64) ctrl (zeroed per launch), [1024, 1024+35K) slot regions
  // (tag-validated: 0xAA poison -> tag 0xAAAA never equals it < 1024 -> no memset).
  unsigned* ctrl = (unsigned*)d_ws;
  unsigned long long* slots = (unsigned long long*)((char*)d_ws + 1024);
  hipMemsetAsync(d_ws, 0, 64, stream);
  fps_kernel<<<dim3(kBlocks), dim3(kThreads), 0, stream>>>(pts, out, slots, ctrl);
}

// Round 13
// 1428.658 us; speedup vs baseline: 1.2647x; 1.2647x over previous
//
#include <hip/hip_runtime.h>

// Furthest Point Sampling, B=8, C=3, N=65536, NUM_POINTS=1024.
//
// R22 = R13 RESTORED VERBATIM (proven best: 1400us; the on-file kernel was
// the regressed R21). This is the final configuration.
//
// TRANSPORT LEDGER -- design space measured CLOSED; R13 is a sharp local
// optimum. Every perturbation regressed:
//   R10  64 pub + 64 poll          +430us
//   R12  64 publishers / 4 lines   +330us  (store churn)
//   R14  64 polling waves          +1240us (4x poll L2 transactions)
//   R19  paired A+B late loads     +25us   (neutral)
//   R20  2-in-flight pipelined poll+240us  (2x poll issue rate)
//   R21  slot-per-cache-line       +360us  (poll loses coalescing: 16
//        transactions/round instead of ONE -- the single hot line is the
//        EFFICIENT config; its 16 stores are absorbed by the L2 write queue)
// Optimum: 16 publishers + 16 serially-polling waves, 16 slots on ONE
// coalesced 128B line per region, XCD-local L2 (sc0) + IC fallback.
//
// Status: latency-bound, not roofline-bound (VALUBusy ~17%, HBM ~0.07%).
// Iteration = ~3270cy: ~550cy VALU + L2 visibility RTT + poll detection +
// LDS handoffs, amplified by max-over-16-blocks scheduling jitter.
//
// Structure (intra-block, all measured wins over R9's 1663us):
//  * DPP reduces everywhere (wave: row_shr 1/2/4/8 + bcast15/31; block:
//    2x quad_perm; slots: quad_perm + mirrors) -- no ds_bpermute chains.
//  * Barrier-free s_wkey handoff: lane-63 ds_write (tag = embedded it),
//    wave0 tag-polls -- no __syncthreads in the loop.
//  * Speculative candidate-coord gather: each wave0 lane gathers its slot
//    candidate's x/y/z under the VALU-only slot reduce; winner coords via
//    ballot + 3 readlane (no dependent uniform load).
//  * Self-tagged 3-word LDS mailbox: waves 1-3 probe three {tag32|val32}
//    words in one LDS round trip, exit with coords in hand.
//
// Placement (init, once): 256 blocks register on per-XCD counters via
// s_getreg(HW_REG_XCC_ID); first 16 on XCD j own batch j; late blocks are
// spares covering vacancies (cross-XCD, served by the IC fallback line).
//
// Regions rotate mod 16, tag-validated (key low 16 bits == it; block skew <
// 2 iterations << 16; 0xAA poison -> tag 0xAAAA never matches it < 1024) ->
// no slot memset (only the 64B ctrl block is zeroed per launch).
//
// Key packing (idx < 65536): dist_bits(32) | (0xFFFF - idx)(16) | it(16).
// Max key = max dist, tie -> smaller index == jnp.argmax first-occurrence
// (dist >= 0 -> float bits monotone; same tag on all keys of an iteration).
// Distance math: __fmul_rn/__fadd_rn (no FMA contraction) to bit-match numpy.

namespace {

constexpr int kB = 8;
constexpr int kN = 65536;
constexpr int kNP = 1024;
constexpr int kPB = 16;                      // slices (blocks) per batch
constexpr int kThreads = 256;
constexpr int kPPT = kN / (kPB * kThreads);  // 16 points per thread
constexpr int kGrp = kPPT / 4;               // 4 float4 groups
constexpr int kWaves = kThreads / 64;        // 4
constexpr int kRgn = 16;                     // region reuse depth (skew < 2)
constexpr int kRgnStride = 32;               // u64: [0:16)=line A (L2), [16:32)=line B (IC)
constexpr int kBlocks = 256;

// One DPP max-reduce step on a u64 key. Invalid-lane handling: old = own
// value, bound_ctrl=false -> lanes with no source keep their own key; if the
// toolchain maps bound_ctrl to "write 0", max(key,0) is also a no-op for
// unsigned keys. Correct without row/bank masks either way.
template <int CTRL>
__device__ __forceinline__ unsigned long long dpp_max_u64(unsigned long long k) {
  const int lo = (int)(unsigned)k;
  const int hi = (int)(unsigned)(k >> 32);
  const unsigned plo = (unsigned)__builtin_amdgcn_update_dpp(lo, lo, CTRL, 0xF, 0xF, false);
  const unsigned phi = (unsigned)__builtin_amdgcn_update_dpp(hi, hi, CTRL, 0xF, 0xF, false);
  const unsigned long long p = ((unsigned long long)phi << 32) | plo;
  return p > k ? p : k;
}

// sc0 load: bypass L1, served by this XCD's L2 (the intra-XCD coherence point).
__device__ __forceinline__ unsigned long long load_l2(const unsigned long long* p) {
  unsigned long long v;
  asm volatile("global_load_dwordx2 %0, %1, off sc0\n\ts_waitcnt vmcnt(0)"
               : "=v"(v)
               : "v"(p)
               : "memory");
  return v;
}

// sc0 store: write-through to this XCD's L2.
__device__ __forceinline__ void store_l2(unsigned long long* p, unsigned long long v) {
  asm volatile("global_store_dwordx2 %0, %1, off sc0" ::"v"(p), "v"(v) : "memory");
}

__global__ __launch_bounds__(kThreads) void fps_kernel(const float* __restrict__ pts,
                                                       float* __restrict__ out,
                                                       unsigned long long* __restrict__ slots,
                                                       unsigned* __restrict__ ctrl) {
  // ctrl: [0:8) per-XCD registration counters, [8] done count, [9] spare rank.
  const int tid = threadIdx.x;
  const int lane = tid & 63;
  const int wave = tid >> 6;

  __shared__ int s_batch, s_slice;
  __shared__ unsigned long long s_wkey[kWaves];  // tag = key low 16 bits (== it)
  __shared__ unsigned long long s_mail[2][3];    // parity x 3 self-tagged {tag32|val32}
  __shared__ int s_hist[kNP];

  if (tid == 0) {
    unsigned xcc;
    asm volatile("s_getreg_b32 %0, hwreg(HW_REG_XCC_ID)" : "=s"(xcc));
    const int home = (int)(xcc & 7u);
    int batch = -1, slice = -1;
    const int pos = (int)atomicAdd(&ctrl[home], 1u);
    if (pos < kPB) {
      batch = home;
      slice = pos;
    }
    __hip_atomic_fetch_add(&ctrl[8], 1u, __ATOMIC_RELEASE, __HIP_MEMORY_SCOPE_AGENT);
    if (batch < 0) {
      while (__hip_atomic_load(&ctrl[8], __ATOMIC_ACQUIRE, __HIP_MEMORY_SCOPE_AGENT) <
             (unsigned)kBlocks) {
        __builtin_amdgcn_s_sleep(8);
      }
      int need = (int)atomicAdd(&ctrl[9], 1u);
      for (int j = 0; j < kB; ++j) {
        int have = (int)__hip_atomic_load(&ctrl[j], __ATOMIC_RELAXED, __HIP_MEMORY_SCOPE_AGENT);
        have = have > kPB ? kPB : have;
        const int vac = kPB - have;
        if (need < vac) {
          batch = j;
          slice = have + need;
          break;
        }
        need -= vac;
      }
    }
    s_batch = batch;
    s_slice = slice;
    // poison: tag 0xFFFF never matches it < 1024
    s_wkey[0] = s_wkey[1] = s_wkey[2] = s_wkey[3] = 0xFFFFull;
    s_mail[0][0] = s_mail[0][1] = s_mail[0][2] = 0xFFFFFFFF00000000ull;
    s_mail[1][0] = s_mail[1][1] = s_mail[1][2] = 0xFFFFFFFF00000000ull;
  }
  __syncthreads();

  const int batch = s_batch;
  const int slice = s_slice;
  if (batch < 0) return;  // unneeded spare

  const float* __restrict__ xb = pts + (size_t)batch * 3 * kN;
  const float* __restrict__ yb = xb + kN;
  const float* __restrict__ zb = xb + 2 * kN;

  // Register-resident coords: block owns [slice*4096, slice*4096+4096).
  const int sbase = slice * (kThreads * kPPT);
  const int base0 = sbase + tid * 4;
  float px[kPPT], py[kPPT], pz[kPPT], dist[kPPT];
#pragma unroll
  for (int g = 0; g < kGrp; ++g) {
    const int base = base0 + g * (kThreads * 4);
    const float4 vx = *reinterpret_cast<const float4*>(xb + base);
    const float4 vy = *reinterpret_cast<const float4*>(yb + base);
    const float4 vz = *reinterpret_cast<const float4*>(zb + base);
    px[g * 4 + 0] = vx.x; px[g * 4 + 1] = vx.y; px[g * 4 + 2] = vx.z; px[g * 4 + 3] = vx.w;
    py[g * 4 + 0] = vy.x; py[g * 4 + 1] = vy.y; py[g * 4 + 2] = vy.z; py[g * 4 + 3] = vy.w;
    pz[g * 4 + 0] = vz.x; pz[g * 4 + 1] = vz.y; pz[g * 4 + 2] = vz.z; pz[g * 4 + 3] = vz.w;
  }
#pragma unroll
  for (int k = 0; k < kPPT; ++k) dist[k] = 1e10f;

  // Seed: index 0 (uniform broadcast load).
  float qx = xb[0], qy = yb[0], qz = zb[0];

  unsigned long long* const sb = slots + (size_t)batch * kRgn * kRgnStride;

  for (int it = 1; it < kNP; ++it) {
    // --- update dists + per-thread argmax (ascending index, strict '>') ---
    float bd = -1.0f;
    int bi = 0;
#pragma unroll
    for (int g = 0; g < kGrp; ++g) {
#pragma unroll
      for (int j = 0; j < 4; ++j) {
        const int k = g * 4 + j;
        const float dx = px[k] - qx;
        const float dy = py[k] - qy;
        const float dz = pz[k] - qz;
        const float ss =
            __fadd_rn(__fadd_rn(__fmul_rn(dx, dx), __fmul_rn(dy, dy)), __fmul_rn(dz, dz));
        const float nd = fminf(dist[k], ss);
        dist[k] = nd;
        if (nd > bd) {
          bd = nd;
          bi = base0 + g * (kThreads * 4) + j;
        }
      }
    }

    // key: dist(32) | (0xFFFF - idx)(16) | it(16)  -- tag self-validates.
    unsigned long long key = ((unsigned long long)__float_as_uint(bd) << 32) |
                             ((unsigned long long)(0xFFFFu - (unsigned)bi) << 16) |
                             (unsigned long long)(unsigned)it;

    // --- wave reduce at VALU speed: row_shr 1/2/4/8 + bcast15/31 -> lane 63 ---
    key = dpp_max_u64<0x111>(key);  // row_shr:1
    key = dpp_max_u64<0x112>(key);  // row_shr:2
    key = dpp_max_u64<0x114>(key);  // row_shr:4
    key = dpp_max_u64<0x118>(key);  // row_shr:8
    key = dpp_max_u64<0x142>(key);  // row_bcast:15
    key = dpp_max_u64<0x143>(key);  // row_bcast:31

    // --- barrier-free handoff: lane 63 ds_writes the wave key (self-tagged) ---
    if (lane == 63) {
      __hip_atomic_store(&s_wkey[wave], key, __ATOMIC_RELAXED, __HIP_MEMORY_SCOPE_WORKGROUP);
    }

    if (wave == 0) {
      // --- tag-poll the 4 wave keys (same-address broadcast, no conflicts) ---
      unsigned long long bk;
      for (;;) {
        bk = __hip_atomic_load(&s_wkey[lane & (kWaves - 1)], __ATOMIC_RELAXED,
                               __HIP_MEMORY_SCOPE_WORKGROUP);
        if (__all((unsigned)(bk & 0xFFFFull) == (unsigned)it)) break;
      }
      // --- block reduce over 4 wave keys: 2x quad_perm xor -> all lanes ---
      bk = dpp_max_u64<0xB1>(bk);  // quad_perm {1,0,3,2} = xor 1
      bk = dpp_max_u64<0x4E>(bk);  // quad_perm {2,3,0,1} = xor 2

      unsigned long long* const rgn = sb + (size_t)(it & (kRgn - 1)) * kRgnStride;
      if (lane == 0) {
        store_l2(rgn + slice, bk);  // primary: XCD-local L2 (measured co-location)
        __hip_atomic_store(rgn + kPB + slice, bk, __ATOMIC_RELAXED,
                           __HIP_MEMORY_SCOPE_AGENT);  // fallback: IC
      }

      // --- poll line A from round 0; merge IC line B from round 2 ---
      unsigned long long sv;
      int round = 0;
      for (;;) {
        unsigned long long a = load_l2(rgn + (lane & (kPB - 1)));
        bool ok = (unsigned)(a & 0xFFFFull) == (unsigned)it;
        if (round >= 2 && !ok) {
          const unsigned long long fb = __hip_atomic_load(
              rgn + kPB + (lane & (kPB - 1)), __ATOMIC_RELAXED, __HIP_MEMORY_SCOPE_AGENT);
          if ((unsigned)(fb & 0xFFFFull) == (unsigned)it) {
            a = fb;
            ok = true;
          }
        }
        if (__all(ok)) {
          sv = a;
          break;
        }
        ++round;
      }

      // --- speculative candidate-coord gather: issued before the VALU-only
      //     slot reduce; the loads complete underneath it ---
      const int cand = (int)(0xFFFFu - ((unsigned)(sv >> 16) & 0xFFFFu));
      const float gx = xb[cand];
      const float gy = yb[cand];
      const float gz = zb[cand];

      // --- 16-slot reduce: xor1, xor2, xor7, xor15 -> all lanes hold winner ---
      unsigned long long k2 = sv;
      k2 = dpp_max_u64<0xB1>(k2);   // quad_perm xor 1
      k2 = dpp_max_u64<0x4E>(k2);   // quad_perm xor 2
      k2 = dpp_max_u64<0x141>(k2);  // row_half_mirror = xor 7
      k2 = dpp_max_u64<0x140>(k2);  // row_mirror = xor 15

      // Winner coords: exactly the lanes whose slot held k2 match; pull their
      // speculative gather via readlane (src is wave-uniform).
      const unsigned long long m = __ballot(sv == k2);
      const int src = (int)__ffsll(m) - 1;
      qx = __int_as_float(__builtin_amdgcn_readlane(__float_as_int(gx), src));
      qy = __int_as_float(__builtin_amdgcn_readlane(__float_as_int(gy), src));
      qz = __int_as_float(__builtin_amdgcn_readlane(__float_as_int(gz), src));

      if (lane == 0) {
        const int p = it & 1;
        const unsigned long long t = (unsigned long long)(unsigned)it << 32;
        __hip_atomic_store(&s_mail[p][0], t | (unsigned)__float_as_uint(qx),
                           __ATOMIC_RELAXED, __HIP_MEMORY_SCOPE_WORKGROUP);
        __hip_atomic_store(&s_mail[p][1], t | (unsigned)__float_as_uint(qy),
                           __ATOMIC_RELAXED, __HIP_MEMORY_SCOPE_WORKGROUP);
        __hip_atomic_store(&s_mail[p][2], t | (unsigned)__float_as_uint(qz),
                           __ATOMIC_RELAXED, __HIP_MEMORY_SCOPE_WORKGROUP);
        s_hist[it] = (int)(0xFFFFu - ((unsigned)(k2 >> 16) & 0xFFFFu));
      }
    } else {
      // --- non-leader waves: probe 3 self-tagged words in one LDS round trip;
      //     exit with coords in hand (no dependent follow-up read) ---
      const int p = it & 1;
      unsigned long long w0, w1, w2;
      do {
        w0 = __hip_atomic_load(&s_mail[p][0], __ATOMIC_RELAXED, __HIP_MEMORY_SCOPE_WORKGROUP);
        w1 = __hip_atomic_load(&s_mail[p][1], __ATOMIC_RELAXED, __HIP_MEMORY_SCOPE_WORKGROUP);
        w2 = __hip_atomic_load(&s_mail[p][2], __ATOMIC_RELAXED, __HIP_MEMORY_SCOPE_WORKGROUP);
      } while (!((unsigned)(w0 >> 32) == (unsigned)it &&
                 (unsigned)(w1 >> 32) == (unsigned)it &&
                 (unsigned)(w2 >> 32) == (unsigned)it));
      qx = __int_as_float((int)(unsigned)w0);
      qy = __int_as_float((int)(unsigned)w1);
      qz = __int_as_float((int)(unsigned)w2);
    }
  }

  __syncthreads();  // make s_hist (written by wave 0) visible to all waves

  // --- gather: out[b][c][j] = points[b][c][idx_j]; slice-0 block per batch ---
  if (slice == 0) {
    float* __restrict__ ob = out + (size_t)batch * 3 * kNP;
    for (int j = tid; j < kNP; j += kThreads) {
      const int id = (j == 0) ? 0 : s_hist[j];
      ob[j] = xb[id];
      ob[kNP + j] = yb[id];
      ob[2 * kNP + j] = zb[id];
    }
  }
}

}  // namespace

extern "C" void kernel_launch(void* const* d_in, const int* in_sizes, int n_in,
                              void* d_out, int out_size, void* d_ws, size_t ws_size,
                              hipStream_t stream) {
  (void)in_sizes;
  (void)n_in;
  (void)out_size;
  (void)ws_size;
  const float* pts = (const float*)d_in[0];
  float* out = (float*)d_out;
  // ws: [0,64) ctrl (zeroed per launch), [1024, 1024+32K) slot regions
  // (tag-validated: 0xAA poison -> tag 0xAAAA never equals it < 1024 -> no memset).
  unsigned* ctrl = (unsigned*)d_ws;
  unsigned long long* slots = (unsigned long long*)((char*)d_ws + 1024);
  hipMemsetAsync(d_ws, 0, 64, stream);
  fps_kernel<<<dim3(kBlocks), dim3(kThreads), 0, stream>>>(pts, out, slots, ctrl);
}